// Round 9
// baseline (217.331 us; speedup 1.0000x reference)
//
#include <hip/hip_runtime.h>

typedef __bf16 bf16_t;
typedef __bf16 bf16x8 __attribute__((ext_vector_type(8)));
typedef float f32x16 __attribute__((ext_vector_type(16)));
typedef unsigned int u32;

#define CTOT 320
#define NPIX 32768  // 8*64*64

// global -> LDS direct DMA, 16 B per lane; LDS dest = wave-uniform base + lane*16
__device__ __forceinline__ void gload16(const void* g, void* l) {
  __builtin_amdgcn_global_load_lds((const __attribute__((address_space(1))) u32*)g,
                                   (__attribute__((address_space(3))) u32*)l, 16, 0, 0);
}

// ---------- P1: y [b][c][h][w] f32 -> yt [pix][320] bf16 (dense, pixel-major)
// ----------                       -> ytp [packed even-checkerboard pix][320]
__global__ __launch_bounds__(256) void k_transpose_y(const float* __restrict__ y,
                                                     bf16_t* __restrict__ yt,
                                                     bf16_t* __restrict__ ytp) {
  __shared__ bf16_t T[64][72];
  int blk = blockIdx.x;            // (8*64) * 5 blocks
  int c0 = (blk % 5) * 64;
  int bh = blk / 5;                // b*64 + h
  int b = bh >> 6, h = bh & 63;
  int tid = threadIdx.x;
  {
    int c = tid >> 2, w0 = (tid & 3) << 4;
    const float* src = y + (size_t)(b * CTOT + c0 + c) * 4096 + (h << 6) + w0;
#pragma unroll
    for (int j = 0; j < 16; j += 4) {
      float4 v = *(const float4*)(src + j);
      T[c][w0 + j + 0] = (bf16_t)v.x;
      T[c][w0 + j + 1] = (bf16_t)v.y;
      T[c][w0 + j + 2] = (bf16_t)v.z;
      T[c][w0 + j + 3] = (bf16_t)v.w;
    }
  }
  __syncthreads();
  {
    int w = tid >> 2, cq = (tid & 3) << 4;
    union { uint4 v; bf16_t b[8]; } u0, u1;
#pragma unroll
    for (int j = 0; j < 8; ++j) { u0.b[j] = T[cq + j][w]; u1.b[j] = T[cq + 8 + j][w]; }
    bf16_t* dst = yt + (size_t)((bh << 6) | w) * CTOT + c0 + cq;
    *(uint4*)dst = u0.v;
    *(uint4*)(dst + 8) = u1.v;
  }
  if (tid < 128) {  // packed copy: w = 2j + (h&1)  (even checkerboard)
    int j = tid >> 2, cq = (tid & 3) << 4;
    int w = (j << 1) + (h & 1);
    union { uint4 v; bf16_t b[8]; } u0, u1;
#pragma unroll
    for (int k = 0; k < 8; ++k) { u0.b[k] = T[cq + k][w]; u1.b[k] = T[cq + 8 + k][w]; }
    bf16_t* dst = ytp + (size_t)((bh << 5) + j) * CTOT + c0 + cq;
    *(uint4*)dst = u0.v;
    *(uint4*)(dst + 8) = u1.v;
  }
}

// ---------- P2: w [oc][ic][5][5] f32 -> wt [tap][icg][OCp][8] bf16 ----------
// (so a 64-lane DMA reads 1 KB contiguous: lane = oc)
__global__ __launch_bounds__(256) void k_transpose_w(const float* __restrict__ w,
                                                     bf16_t* __restrict__ wt,
                                                     int IC, int OC, int OCp) {
  int idx = blockIdx.x * 256 + threadIdx.x;
  if (idx >= OCp * IC) return;
  int oc = idx / IC, ic = idx - oc * IC;
  bool valid = (oc < OC);
  const float* src = w + (size_t)(oc * IC + ic) * 25;
  int icg = ic >> 3, ie = ic & 7;
#pragma unroll
  for (int t = 0; t < 25; ++t) {
    float v = valid ? src[t] : 0.0f;
    wt[(size_t)((t * (IC >> 3) + icg) * OCp + oc) * 8 + ie] = (bf16_t)v;
  }
}

__global__ void k_zero(uint4* z) { z[threadIdx.x] = uint4{0u, 0u, 0u, 0u}; }

// ---------- main: implicit-GEMM conv, 32x32x16 MFMA, K-chunk=16,
// 16 waves/block (4/SIMD), single-buffered Sin+Sw staged via global_load_lds DMA.
struct ConvDesc {
  const float* bias;
  int out_off, wt_off;
  int ICp, OC, OCp, chs, masked, job_start;
};
struct MainParams {
  const bf16_t* yt;
  const bf16_t* ytp;
  const bf16_t* wt;
  const bf16_t* zp;   // 1 KB of zeros (DMA source for halo/pad)
  float* out;
  ConvDesc cv[9];
};

template <bool MASKED>
__device__ __forceinline__ void conv_run(const ConvDesc cd, const MainParams& P,
                                         int local, bf16_t* S) {
  constexpr int NT   = MASKED ? 12 : 25;
  constexpr int COLS = MASKED ? 36 : 68;
  constexpr int REAL = MASKED ? 1296 : 1360;  // real slots per plane (36x36 / 20x68)
  constexpr int NSG  = MASKED ? 21 : 22;      // 64-slot DMA groups per plane
  constexpr int SPL  = NSG * 512;             // plane stride (el)
  constexpr int SWO  = 2 * SPL;               // Sw offset

  // unmasked: block = 64 oc x 1024 px (16 rows); masked: 64 oc x 32 out-rows
  int mb = MASKED ? (local >> 4) : (local >> 5);
  int nb = local & (MASKED ? 15 : 31);
  int b  = MASKED ? (nb >> 1) : (nb >> 2);
  int hblk = MASKED ? ((nb & 1) << 5) : ((nb & 3) << 4);
  int tid = threadIdx.x, lane = tid & 63, wid = tid >> 6;
  int l31 = lane & 31, kq = lane >> 5;

  int octmax = (cd.OC - (mb << 6)) >> 5; if (octmax > 2) octmax = 2;

  f32x16 acc00 = {}, acc01 = {}, acc10 = {}, acc11 = {};

  int aofs = SWO + kq * 512 + l31 * 8;
  int bofs = kq * SPL + (MASKED ? (((wid << 1) * 36 + 1 + l31) * 8)
                                : ((wid * 68 + l31) * 8));

  const bf16_t* wtc = P.wt + cd.wt_off;
  int icgs = cd.ICp >> 3;
  int nchunks = cd.ICp >> 4;

  auto stage = [&](int cb) {
    int ic0 = cb << 4;
    // Sin: 2 planes (icg), NSG wave-groups each; lane -> slot, dest linear
    for (int g = wid; g < 2 * NSG; g += 16) {
      int p = (g >= NSG) ? 1 : 0;
      int gi = g - p * NSG;
      int s = (gi << 6) + lane;
      int rr = s / COLS, cc = s - rr * COLS;
      int h = hblk + rr - 2;
      const bf16_t* gp;
      if (!MASKED) {
        int w = cc - 2;
        bool inb = (s < REAL) && ((unsigned)h < 64u) && ((unsigned)w < 64u);
        gp = inb ? (P.yt + (size_t)((((b << 6) + (h & 63)) << 6) | (w & 63)) * CTOT
                        + cd.chs + ic0 + (p << 3))
                 : P.zp;
      } else {
        int j = cc - 1;
        bool inb = (s < REAL) && ((unsigned)h < 64u) && ((unsigned)j < 32u);
        gp = inb ? (P.ytp + (size_t)((((b << 6) + (h & 63)) << 5) + (j & 31)) * CTOT
                         + cd.chs + ic0 + (p << 3))
                 : P.zp;
      }
      gload16(gp, S + p * SPL + (gi << 9));
    }
    // Sw: 2*NT wave-groups; lane = oc, global 1 KB contiguous, dest linear
    for (int g = wid; g < 2 * NT; g += 16) {
      int slot = g >> 1, icg = g & 1;
      int tap = MASKED ? (2 * slot + 1) : slot;
      const bf16_t* gp = wtc +
          (size_t)((tap * icgs + (ic0 >> 3) + icg) * cd.OCp + (mb << 6) + lane) * 8;
      gload16(gp, S + SWO + (g << 9));
    }
  };

  for (int cb = 0; cb < nchunks; ++cb) {
    stage(cb);
    __syncthreads();                          // drains vmcnt: buffer ready

#define TAP_ONE(TI)                                                             \
    {                                                                           \
      int tap_ = MASKED ? (2 * (TI) + 1) : (TI);                                \
      int dy_ = tap_ / 5, dx_ = tap_ % 5;                                       \
      bf16x8 af0 = *(const bf16x8*)(S + aofs + (TI) * 1024);                    \
      bf16x8 bf0, bf1;                                                          \
      if (!MASKED) {                                                            \
        int toff_ = (dy_ * 68 + dx_) * 8;                                       \
        bf0 = *(const bf16x8*)(S + bofs + toff_);                               \
        bf1 = *(const bf16x8*)(S + bofs + toff_ + 256);                         \
      } else {                                                                  \
        int j0_ = (dx_ - 1 - (dy_ & 1)) / 2;                                    \
        int j1_ = (dx_ - 2 - ((dy_ + 1) & 1)) / 2;                              \
        bf0 = *(const bf16x8*)(S + bofs + (dy_ * 36 + j0_) * 8);                \
        bf1 = *(const bf16x8*)(S + bofs + ((dy_ + 1) * 36 + j1_) * 8);          \
      }                                                                         \
      acc00 = __builtin_amdgcn_mfma_f32_32x32x16_bf16(af0, bf0, acc00, 0, 0, 0);\
      acc01 = __builtin_amdgcn_mfma_f32_32x32x16_bf16(af0, bf1, acc01, 0, 0, 0);\
      if (octmax > 1) {                                                         \
        bf16x8 af1 = *(const bf16x8*)(S + aofs + (TI) * 1024 + 256);            \
        acc10 = __builtin_amdgcn_mfma_f32_32x32x16_bf16(af1, bf0, acc10, 0,0,0);\
        acc11 = __builtin_amdgcn_mfma_f32_32x32x16_bf16(af1, bf1, acc11, 0,0,0);\
      }                                                                         \
    }
#pragma unroll
    for (int s = 0; s < NT; ++s) TAP_ONE(s)
#undef TAP_ONE
    __syncthreads();                          // protect buffer overwrite
  }

  // ---- epilogue: bias (+ parity packing for masked) ----
  float* outp = P.out + cd.out_off;
#define EPI_U(A, OT, PT)                                                        \
  {                                                                             \
    int h = hblk + wid;                                                         \
    _Pragma("unroll")                                                           \
    for (int r = 0; r < 16; ++r) {                                              \
      int row = (r & 3) + ((r >> 2) << 3) + (kq << 2);                          \
      int oc = (mb << 6) + ((OT) << 5) + row;                                   \
      outp[(size_t)(b * cd.OC + oc) * 4096 + (h << 6) + ((PT) << 5) + l31] =    \
          (A)[r] + cd.bias[oc];                                                 \
    }                                                                           \
  }
#define EPI_M(A, OT, PT)                                                        \
  {                                                                             \
    int h = hblk + (wid << 1) + (PT);                                           \
    _Pragma("unroll")                                                           \
    for (int r = 0; r < 16; ++r) {                                              \
      int row = (r & 3) + ((r >> 2) << 3) + (kq << 2);                          \
      int oc = (mb << 6) + ((OT) << 5) + row;                                   \
      float val = (A)[r] + cd.bias[oc];                                         \
      float2 pr;                                                                \
      if ((PT) == 0) { pr.x = 0.0f; pr.y = val; }                               \
      else           { pr.x = val;  pr.y = 0.0f; }                              \
      *(float2*)(outp + (size_t)(b * cd.OC + oc) * 4096 + (h << 6) + (l31 << 1)) = pr; \
    }                                                                           \
  }
  if (!MASKED) {
    EPI_U(acc00, 0, 0); EPI_U(acc01, 0, 1);
    if (octmax > 1) { EPI_U(acc10, 1, 0); EPI_U(acc11, 1, 1); }
  } else {
    EPI_M(acc00, 0, 0); EPI_M(acc01, 0, 1);
    if (octmax > 1) { EPI_M(acc10, 1, 0); EPI_M(acc11, 1, 1); }
  }
#undef EPI_U
#undef EPI_M
}

__global__ __launch_bounds__(1024) void k_conv_main(MainParams P) {
  __shared__ bf16_t S[48128];   // 96256 B: Sin 2x11264 + Sw 25x1024 (unmasked max)
  int bid = blockIdx.x;
  int ci = 0;
#pragma unroll
  for (int i = 1; i < 9; ++i) if (bid >= P.cv[i].job_start) ci = i;
  ConvDesc cd = P.cv[ci];
  int local = bid - cd.job_start;
  if (cd.masked) conv_run<true>(cd, P, local, S);
  else           conv_run<false>(cd, P, local, S);
}

extern "C" void kernel_launch(void* const* d_in, const int* in_sizes, int n_in,
                              void* d_out, int out_size, void* d_ws, size_t ws_size,
                              hipStream_t stream) {
  const float* y = (const float*)d_in[0];
  bf16_t* yt  = (bf16_t*)d_ws;                               // 10,485,760 el
  bf16_t* ytp = yt + (size_t)NPIX * CTOT;                    // +5,242,880 el
  bf16_t* wt  = ytp + (size_t)(NPIX / 2) * CTOT;             // +3,660,800 el
  bf16_t* zp  = wt + 3660800;                                // +512 el (1 KB zeros)

  k_transpose_y<<<2560, 256, 0, stream>>>(y, yt, ytp);
  k_zero<<<1, 64, 0, stream>>>((uint4*)zp);

  // Heaviest-first:      ch4      sp4     ch3     ch2     ch1     sp3     sp2     sp1    sp0
  static const int ICv[9]  = {128,    192,    64,     32,     16,     64,     32,     16,    16};
  static const int OCv[9]  = {384,    384,    128,    64,     32,     128,    64,     32,    32};
  static const int OCp[9]  = {384,    384,    128,    64,     64,     128,    64,     64,    64};
  static const int WIDX[9] = {19,     11,     17,     15,     13,     9,      7,      5,     3};
  static const int BIDX[9] = {20,     12,     18,     16,     14,     10,     8,      6,     4};
  static const int CHS[9]  = {0,      128,    0,      0,      0,      64,     32,     16,    0};
  static const int MSK[9]  = {0,      1,      0,      0,      0,      1,      1,      1,     1};
  static const int WTOFF[9] = {0, 1228800, 3072000, 3276800, 3328000,
                               3353600, 3558400, 3609600, 3635200};
  static const int OUTOFF[9] = {28311552, 15728640, 11534336, 5242880, 2097152,
                                7340032,  3145728,  1048576,  0};
  // blocks: unmasked (OCp/64)*32, masked (OCp/64)*16
  static const int JOBST[9] = {0, 192, 288, 352, 384, 416, 448, 464, 480};  // total 496

  for (int i = 0; i < 9; ++i) {
    int n = OCp[i] * ICv[i];
    k_transpose_w<<<(n + 255) / 256, 256, 0, stream>>>(
        (const float*)d_in[WIDX[i]], wt + WTOFF[i], ICv[i], OCv[i], OCp[i]);
  }

  MainParams P;
  P.yt = yt; P.ytp = ytp; P.wt = wt; P.zp = zp; P.out = (float*)d_out;
  for (int i = 0; i < 9; ++i) {
    P.cv[i].bias = (const float*)d_in[BIDX[i]];
    P.cv[i].out_off = OUTOFF[i];
    P.cv[i].wt_off = WTOFF[i];
    P.cv[i].ICp = ICv[i]; P.cv[i].OC = OCv[i]; P.cv[i].OCp = OCp[i];
    P.cv[i].chs = CHS[i]; P.cv[i].masked = MSK[i];
    P.cv[i].job_start = JOBST[i];
  }
  k_conv_main<<<496, 1024, 0, stream>>>(P);
}

// Round 10
// 206.728 us; speedup vs baseline: 1.0513x; 1.0513x over previous
//
#include <hip/hip_runtime.h>

typedef __bf16 bf16_t;
typedef __bf16 bf16x8 __attribute__((ext_vector_type(8)));
typedef float f32x16 __attribute__((ext_vector_type(16)));
typedef unsigned int u32;

#define CTOT 320
#define NPIX 32768  // 8*64*64

// global -> LDS direct DMA, 16 B per lane; LDS dest = wave-uniform base + lane*16
__device__ __forceinline__ void gload16(const void* g, void* l) {
  __builtin_amdgcn_global_load_lds((const __attribute__((address_space(1))) u32*)g,
                                   (__attribute__((address_space(3))) u32*)l, 16, 0, 0);
}

// ---------- P1: y [b][c][h][w] f32 -> yt [pix][320] bf16 (dense, pixel-major)
// ----------                       -> ytp [packed even-checkerboard pix][320]
__global__ __launch_bounds__(256) void k_transpose_y(const float* __restrict__ y,
                                                     bf16_t* __restrict__ yt,
                                                     bf16_t* __restrict__ ytp) {
  __shared__ bf16_t T[64][72];
  int blk = blockIdx.x;            // (8*64) * 5 blocks
  int c0 = (blk % 5) * 64;
  int bh = blk / 5;                // b*64 + h
  int b = bh >> 6, h = bh & 63;
  int tid = threadIdx.x;
  {
    int c = tid >> 2, w0 = (tid & 3) << 4;
    const float* src = y + (size_t)(b * CTOT + c0 + c) * 4096 + (h << 6) + w0;
#pragma unroll
    for (int j = 0; j < 16; j += 4) {
      float4 v = *(const float4*)(src + j);
      T[c][w0 + j + 0] = (bf16_t)v.x;
      T[c][w0 + j + 1] = (bf16_t)v.y;
      T[c][w0 + j + 2] = (bf16_t)v.z;
      T[c][w0 + j + 3] = (bf16_t)v.w;
    }
  }
  __syncthreads();
  {
    int w = tid >> 2, cq = (tid & 3) << 4;
    union { uint4 v; bf16_t b[8]; } u0, u1;
#pragma unroll
    for (int j = 0; j < 8; ++j) { u0.b[j] = T[cq + j][w]; u1.b[j] = T[cq + 8 + j][w]; }
    bf16_t* dst = yt + (size_t)((bh << 6) | w) * CTOT + c0 + cq;
    *(uint4*)dst = u0.v;
    *(uint4*)(dst + 8) = u1.v;
  }
  if (tid < 128) {  // packed copy: w = 2j + (h&1)  (even checkerboard)
    int j = tid >> 2, cq = (tid & 3) << 4;
    int w = (j << 1) + (h & 1);
    union { uint4 v; bf16_t b[8]; } u0, u1;
#pragma unroll
    for (int k = 0; k < 8; ++k) { u0.b[k] = T[cq + k][w]; u1.b[k] = T[cq + 8 + k][w]; }
    bf16_t* dst = ytp + (size_t)((bh << 5) + j) * CTOT + c0 + cq;
    *(uint4*)dst = u0.v;
    *(uint4*)(dst + 8) = u1.v;
  }
}

// ---------- P2: w [oc][ic][5][5] f32 -> wt [tap][icg][OCp][8] bf16 ----------
// (so a 64-lane DMA reads 1 KB contiguous: lane = oc)
__global__ __launch_bounds__(256) void k_transpose_w(const float* __restrict__ w,
                                                     bf16_t* __restrict__ wt,
                                                     int IC, int OC, int OCp) {
  int idx = blockIdx.x * 256 + threadIdx.x;
  if (idx >= OCp * IC) return;
  int oc = idx / IC, ic = idx - oc * IC;
  bool valid = (oc < OC);
  const float* src = w + (size_t)(oc * IC + ic) * 25;
  int icg = ic >> 3, ie = ic & 7;
#pragma unroll
  for (int t = 0; t < 25; ++t) {
    float v = valid ? src[t] : 0.0f;
    wt[(size_t)((t * (IC >> 3) + icg) * OCp + oc) * 8 + ie] = (bf16_t)v;
  }
}

__global__ void k_zero(uint4* z) { z[threadIdx.x] = uint4{0u, 0u, 0u, 0u}; }

// ---------- main: implicit-GEMM conv, 32x32x16 MFMA, K-chunk=16, 16 waves.
// Sin double-buffered; Sw time-alternated (A group staged during tapsB, B during
// tapsA) -> every DMA hides under ~half-chunk of MFMA; 2 barriers/chunk.
struct ConvDesc {
  const float* bias;
  int out_off, wt_off;
  int ICp, OC, OCp, chs, masked, job_start;
};
struct MainParams {
  const bf16_t* yt;
  const bf16_t* ytp;
  const bf16_t* wt;
  const bf16_t* zp;   // 1 KB of zeros (DMA source for halo/pad)
  float* out;
  ConvDesc cv[9];
};

template <bool MASKED>
__device__ __forceinline__ void conv_run(const ConvDesc cd, const MainParams& P,
                                         int local, bf16_t* S) {
  constexpr int NT   = MASKED ? 12 : 25;
  constexpr int NTA  = MASKED ? 6 : 13;
  constexpr int NTB  = NT - NTA;              // 6 / 12
  constexpr int COLS = MASKED ? 36 : 68;
  constexpr int REAL = MASKED ? 1296 : 1360;  // real slots per plane (36x36 / 20x68)
  constexpr int NSG  = MASKED ? 21 : 22;      // 64-slot DMA groups per plane
  constexpr int SPL  = NSG * 512;             // plane stride (el)
  constexpr int SINB = 2 * SPL;               // Sin buffer (2 icg planes)
  constexpr int SWO  = 2 * SINB;              // Sw offset (after both Sin buffers)

  // unmasked: block = 64 oc x 1024 px (16 rows); masked: 64 oc x 32 out-rows
  int mb = MASKED ? (local >> 4) : (local >> 5);
  int nb = local & (MASKED ? 15 : 31);
  int b  = MASKED ? (nb >> 1) : (nb >> 2);
  int hblk = MASKED ? ((nb & 1) << 5) : ((nb & 3) << 4);
  int tid = threadIdx.x, lane = tid & 63, wid = tid >> 6;
  int l31 = lane & 31, kq = lane >> 5;

  int octmax = (cd.OC - (mb << 6)) >> 5; if (octmax > 2) octmax = 2;

  f32x16 acc00 = {}, acc01 = {}, acc10 = {}, acc11 = {};

  int aofs = SWO + kq * 512 + l31 * 8;
  int bofs = kq * SPL + (MASKED ? (((wid << 1) * 36 + 1 + l31) * 8)
                                : ((wid * 68 + l31) * 8));

  const bf16_t* wtc = P.wt + cd.wt_off;
  int icgs = cd.ICp >> 3;
  int nchunks = cd.ICp >> 4;

  auto stage_sin = [&](int cb, int buf) {
    int ic0 = cb << 4;
    for (int g = wid; g < 2 * NSG; g += 16) {
      int p = (g >= NSG) ? 1 : 0;
      int gi = g - p * NSG;
      int s = (gi << 6) + lane;
      int rr = s / COLS, cc = s - rr * COLS;
      int h = hblk + rr - 2;
      const bf16_t* gp;
      if (!MASKED) {
        int w = cc - 2;
        bool inb = (s < REAL) && ((unsigned)h < 64u) && ((unsigned)w < 64u);
        gp = inb ? (P.yt + (size_t)((((b << 6) + (h & 63)) << 6) | (w & 63)) * CTOT
                        + cd.chs + ic0 + (p << 3))
                 : P.zp;
      } else {
        int j = cc - 1;
        bool inb = (s < REAL) && ((unsigned)h < 64u) && ((unsigned)j < 32u);
        gp = inb ? (P.ytp + (size_t)((((b << 6) + (h & 63)) << 5) + (j & 31)) * CTOT
                         + cd.chs + ic0 + (p << 3))
                 : P.zp;
      }
      gload16(gp, S + buf * SINB + p * SPL + (gi << 9));
    }
  };
  // group A: slots 0..NTA-1; group B: slots NTA..NT-1
  auto stage_swA = [&](int cb) {
    int ic0 = cb << 4;
    for (int g = wid; g < 2 * NTA; g += 16) {
      int slot = g >> 1, icg = g & 1;
      int tap = MASKED ? (2 * slot + 1) : slot;
      const bf16_t* gp = wtc +
          (size_t)((tap * icgs + (ic0 >> 3) + icg) * cd.OCp + (mb << 6) + lane) * 8;
      gload16(gp, S + SWO + (g << 9));
    }
  };
  auto stage_swB = [&](int cb) {
    int ic0 = cb << 4;
    for (int g = wid; g < 2 * NTB; g += 16) {
      int slot = g >> 1, icg = g & 1;
      int tap = MASKED ? (2 * (NTA + slot) + 1) : (NTA + slot);
      const bf16_t* gp = wtc +
          (size_t)((tap * icgs + (ic0 >> 3) + icg) * cd.OCp + (mb << 6) + lane) * 8;
      gload16(gp, S + SWO + ((2 * NTA + g) << 9));
    }
  };

#define TAP_ONE(TI)                                                             \
    {                                                                           \
      int tap_ = MASKED ? (2 * (TI) + 1) : (TI);                                \
      int dy_ = tap_ / 5, dx_ = tap_ % 5;                                       \
      bf16x8 af0 = *(const bf16x8*)(Sb + aofs + (TI) * 1024);                   \
      bf16x8 bf0, bf1;                                                          \
      if (!MASKED) {                                                            \
        int toff_ = (dy_ * 68 + dx_) * 8;                                       \
        bf0 = *(const bf16x8*)(Sn + bofs + toff_);                              \
        bf1 = *(const bf16x8*)(Sn + bofs + toff_ + 256);                        \
      } else {                                                                  \
        int j0_ = (dx_ - 1 - (dy_ & 1)) / 2;                                    \
        int j1_ = (dx_ - 2 - ((dy_ + 1) & 1)) / 2;                              \
        bf0 = *(const bf16x8*)(Sn + bofs + (dy_ * 36 + j0_) * 8);               \
        bf1 = *(const bf16x8*)(Sn + bofs + ((dy_ + 1) * 36 + j1_) * 8);         \
      }                                                                         \
      acc00 = __builtin_amdgcn_mfma_f32_32x32x16_bf16(af0, bf0, acc00, 0, 0, 0);\
      acc01 = __builtin_amdgcn_mfma_f32_32x32x16_bf16(af0, bf1, acc01, 0, 0, 0);\
      if (octmax > 1) {                                                         \
        bf16x8 af1 = *(const bf16x8*)(Sb + aofs + (TI) * 1024 + 256);           \
        acc10 = __builtin_amdgcn_mfma_f32_32x32x16_bf16(af1, bf0, acc10, 0,0,0);\
        acc11 = __builtin_amdgcn_mfma_f32_32x32x16_bf16(af1, bf1, acc11, 0,0,0);\
      }                                                                         \
    }

  stage_swA(0);
  stage_sin(0, 0);
  for (int cb = 0; cb < nchunks; ++cb) {
    const bf16_t* Sb = S;                      // Sw base (aofs includes SWO)
    const bf16_t* Sn = S + (cb & 1) * SINB;    // Sin buffer for this chunk
    __syncthreads();                           // drains: Sin(cb), SwA(cb)
    if (cb + 1 < nchunks) stage_sin(cb + 1, (cb + 1) & 1);
    stage_swB(cb);                             // lands under tapsA
#pragma unroll
    for (int s = 0; s < NTA; ++s) TAP_ONE(s)
    __syncthreads();                           // drains: SwB(cb) (+Sin ahead)
    if (cb + 1 < nchunks) stage_swA(cb + 1);   // lands under tapsB
#pragma unroll
    for (int s = NTA; s < NT; ++s) TAP_ONE(s)
  }
#undef TAP_ONE

  // ---- epilogue: bias (+ parity packing for masked) ----
  float* outp = P.out + cd.out_off;
#define EPI_U(A, OT, PT)                                                        \
  {                                                                             \
    int h = hblk + wid;                                                         \
    _Pragma("unroll")                                                           \
    for (int r = 0; r < 16; ++r) {                                              \
      int row = (r & 3) + ((r >> 2) << 3) + (kq << 2);                          \
      int oc = (mb << 6) + ((OT) << 5) + row;                                   \
      outp[(size_t)(b * cd.OC + oc) * 4096 + (h << 6) + ((PT) << 5) + l31] =    \
          (A)[r] + cd.bias[oc];                                                 \
    }                                                                           \
  }
#define EPI_M(A, OT, PT)                                                        \
  {                                                                             \
    int h = hblk + (wid << 1) + (PT);                                           \
    _Pragma("unroll")                                                           \
    for (int r = 0; r < 16; ++r) {                                              \
      int row = (r & 3) + ((r >> 2) << 3) + (kq << 2);                          \
      int oc = (mb << 6) + ((OT) << 5) + row;                                   \
      float val = (A)[r] + cd.bias[oc];                                         \
      float2 pr;                                                                \
      if ((PT) == 0) { pr.x = 0.0f; pr.y = val; }                               \
      else           { pr.x = val;  pr.y = 0.0f; }                              \
      *(float2*)(outp + (size_t)(b * cd.OC + oc) * 4096 + (h << 6) + (l31 << 1)) = pr; \
    }                                                                           \
  }
  if (!MASKED) {
    EPI_U(acc00, 0, 0); EPI_U(acc01, 0, 1);
    if (octmax > 1) { EPI_U(acc10, 1, 0); EPI_U(acc11, 1, 1); }
  } else {
    EPI_M(acc00, 0, 0); EPI_M(acc01, 0, 1);
    if (octmax > 1) { EPI_M(acc10, 1, 0); EPI_M(acc11, 1, 1); }
  }
#undef EPI_U
#undef EPI_M
}

__global__ __launch_bounds__(1024) void k_conv_main(MainParams P) {
  // unmasked: Sin 2x22528 + Sw 25600 = 70656 el = 141312 B (<160K, 1 blk/CU, 16 waves)
  __shared__ bf16_t S[70656];
  int bid = blockIdx.x;
  int ci = 0;
#pragma unroll
  for (int i = 1; i < 9; ++i) if (bid >= P.cv[i].job_start) ci = i;
  ConvDesc cd = P.cv[ci];
  int local = bid - cd.job_start;
  if (cd.masked) conv_run<true>(cd, P, local, S);
  else           conv_run<false>(cd, P, local, S);
}

extern "C" void kernel_launch(void* const* d_in, const int* in_sizes, int n_in,
                              void* d_out, int out_size, void* d_ws, size_t ws_size,
                              hipStream_t stream) {
  const float* y = (const float*)d_in[0];
  bf16_t* yt  = (bf16_t*)d_ws;                               // 10,485,760 el
  bf16_t* ytp = yt + (size_t)NPIX * CTOT;                    // +5,242,880 el
  bf16_t* wt  = ytp + (size_t)(NPIX / 2) * CTOT;             // +3,660,800 el
  bf16_t* zp  = wt + 3660800;                                // +512 el (1 KB zeros)

  k_transpose_y<<<2560, 256, 0, stream>>>(y, yt, ytp);
  k_zero<<<1, 64, 0, stream>>>((uint4*)zp);

  // Heaviest-first:      ch4      sp4     ch3     ch2     ch1     sp3     sp2     sp1    sp0
  static const int ICv[9]  = {128,    192,    64,     32,     16,     64,     32,     16,    16};
  static const int OCv[9]  = {384,    384,    128,    64,     32,     128,    64,     32,    32};
  static const int OCp[9]  = {384,    384,    128,    64,     64,     128,    64,     64,    64};
  static const int WIDX[9] = {19,     11,     17,     15,     13,     9,      7,      5,     3};
  static const int BIDX[9] = {20,     12,     18,     16,     14,     10,     8,      6,     4};
  static const int CHS[9]  = {0,      128,    0,      0,      0,      64,     32,     16,    0};
  static const int MSK[9]  = {0,      1,      0,      0,      0,      1,      1,      1,     1};
  static const int WTOFF[9] = {0, 1228800, 3072000, 3276800, 3328000,
                               3353600, 3558400, 3609600, 3635200};
  static const int OUTOFF[9] = {28311552, 15728640, 11534336, 5242880, 2097152,
                                7340032,  3145728,  1048576,  0};
  // blocks: unmasked (OCp/64)*32, masked (OCp/64)*16
  static const int JOBST[9] = {0, 192, 288, 352, 384, 416, 448, 464, 480};  // total 496

  for (int i = 0; i < 9; ++i) {
    int n = OCp[i] * ICv[i];
    k_transpose_w<<<(n + 255) / 256, 256, 0, stream>>>(
        (const float*)d_in[WIDX[i]], wt + WTOFF[i], ICv[i], OCv[i], OCp[i]);
  }

  MainParams P;
  P.yt = yt; P.ytp = ytp; P.wt = wt; P.zp = zp; P.out = (float*)d_out;
  for (int i = 0; i < 9; ++i) {
    P.cv[i].bias = (const float*)d_in[BIDX[i]];
    P.cv[i].out_off = OUTOFF[i];
    P.cv[i].wt_off = WTOFF[i];
    P.cv[i].ICp = ICv[i]; P.cv[i].OC = OCv[i]; P.cv[i].OCp = OCp[i];
    P.cv[i].chs = CHS[i]; P.cv[i].masked = MSK[i];
    P.cv[i].job_start = JOBST[i];
  }
  k_conv_main<<<496, 1024, 0, stream>>>(P);
}

// Round 11
// 186.786 us; speedup vs baseline: 1.1635x; 1.1068x over previous
//
#include <hip/hip_runtime.h>

typedef __bf16 bf16_t;
typedef __bf16 bf16x8 __attribute__((ext_vector_type(8)));
typedef float f32x16 __attribute__((ext_vector_type(16)));
typedef unsigned int u32;

#define CTOT 320
#define NPIX 32768  // 8*64*64

// global -> LDS direct DMA, 16 B per lane; LDS dest = wave-uniform base + lane*16
__device__ __forceinline__ void gload16(const void* g, void* l) {
  __builtin_amdgcn_global_load_lds((const __attribute__((address_space(1))) u32*)g,
                                   (__attribute__((address_space(3))) u32*)l, 16, 0, 0);
}

// ---------- P1: y [b][c][h][w] f32 -> yt [pix][320] bf16 (dense, pixel-major)
// ----------                       -> ytp [packed even-checkerboard pix][320]
__global__ __launch_bounds__(256) void k_transpose_y(const float* __restrict__ y,
                                                     bf16_t* __restrict__ yt,
                                                     bf16_t* __restrict__ ytp) {
  __shared__ bf16_t T[64][72];
  int blk = blockIdx.x;            // (8*64) * 5 blocks
  int c0 = (blk % 5) * 64;
  int bh = blk / 5;                // b*64 + h
  int b = bh >> 6, h = bh & 63;
  int tid = threadIdx.x;
  {
    int c = tid >> 2, w0 = (tid & 3) << 4;
    const float* src = y + (size_t)(b * CTOT + c0 + c) * 4096 + (h << 6) + w0;
#pragma unroll
    for (int j = 0; j < 16; j += 4) {
      float4 v = *(const float4*)(src + j);
      T[c][w0 + j + 0] = (bf16_t)v.x;
      T[c][w0 + j + 1] = (bf16_t)v.y;
      T[c][w0 + j + 2] = (bf16_t)v.z;
      T[c][w0 + j + 3] = (bf16_t)v.w;
    }
  }
  __syncthreads();
  {
    int w = tid >> 2, cq = (tid & 3) << 4;
    union { uint4 v; bf16_t b[8]; } u0, u1;
#pragma unroll
    for (int j = 0; j < 8; ++j) { u0.b[j] = T[cq + j][w]; u1.b[j] = T[cq + 8 + j][w]; }
    bf16_t* dst = yt + (size_t)((bh << 6) | w) * CTOT + c0 + cq;
    *(uint4*)dst = u0.v;
    *(uint4*)(dst + 8) = u1.v;
  }
  if (tid < 128) {  // packed copy: w = 2j + (h&1)  (even checkerboard)
    int j = tid >> 2, cq = (tid & 3) << 4;
    int w = (j << 1) + (h & 1);
    union { uint4 v; bf16_t b[8]; } u0, u1;
#pragma unroll
    for (int k = 0; k < 8; ++k) { u0.b[k] = T[cq + k][w]; u1.b[k] = T[cq + 8 + k][w]; }
    bf16_t* dst = ytp + (size_t)((bh << 5) + j) * CTOT + c0 + cq;
    *(uint4*)dst = u0.v;
    *(uint4*)(dst + 8) = u1.v;
  }
}

// ---------- P2: w [oc][ic][5][5] f32 -> wt [tap][icg][OCp][8] bf16 ----------
// (so a 64-lane DMA reads 1 KB contiguous: lane = oc)
__global__ __launch_bounds__(256) void k_transpose_w(const float* __restrict__ w,
                                                     bf16_t* __restrict__ wt,
                                                     int IC, int OC, int OCp) {
  int idx = blockIdx.x * 256 + threadIdx.x;
  if (idx >= OCp * IC) return;
  int oc = idx / IC, ic = idx - oc * IC;
  bool valid = (oc < OC);
  const float* src = w + (size_t)(oc * IC + ic) * 25;
  int icg = ic >> 3, ie = ic & 7;
#pragma unroll
  for (int t = 0; t < 25; ++t) {
    float v = valid ? src[t] : 0.0f;
    wt[(size_t)((t * (IC >> 3) + icg) * OCp + oc) * 8 + ie] = (bf16_t)v;
  }
}

__global__ void k_zero(uint4* z) { z[threadIdx.x] = uint4{0u, 0u, 0u, 0u}; }

// ---------- main: implicit-GEMM conv, 32x32x16 MFMA, K-chunk=16, 8 waves/block,
// 2 blocks/CU (cross-block overlap), DMA staging with per-group prefetch:
// every barrier drains only loads issued one tap-group (~6 taps) earlier.
struct ConvDesc {
  const float* bias;
  int out_off, wt_off;
  int IC, OC, OCp, chs, masked, job_start;
};
struct MainParams {
  const bf16_t* yt;
  const bf16_t* ytp;
  const bf16_t* wt;
  const bf16_t* zp;   // 1 KB of zeros (DMA source for halo/pad)
  float* out;
  ConvDesc cv[9];
};

template <bool MASKED>
__device__ __forceinline__ void conv_run(const ConvDesc cd, const MainParams& P,
                                         int local, bf16_t* S) {
  constexpr int COLS = MASKED ? 36 : 68;
  constexpr int REAL = MASKED ? 720 : 816;   // real pixel slots per plane
  constexpr int NSG  = MASKED ? 12 : 13;     // 64-slot DMA groups per plane
  constexpr int SPL  = NSG * 512;            // plane stride (el)
  constexpr int SINB = 2 * SPL;              // Sin buffer (2 icg planes)
  constexpr int SWO  = 2 * SINB;             // Sw offset (after both Sin buffers)
  // Sw: 14 slots x 1024 el (two 7-slot group buffers, alternating)

  // unmasked: block = 64 oc x 512 px (8 rows); masked: 64 oc x 16 out-rows
  int mb = MASKED ? (local >> 5) : (local >> 6);
  int nb = local & (MASKED ? 31 : 63);
  int b  = MASKED ? (nb >> 2) : (nb >> 3);
  int hblk = MASKED ? ((nb & 3) << 4) : ((nb & 7) << 3);
  int tid = threadIdx.x, lane = tid & 63, wid = tid >> 6;
  int l31 = lane & 31, kq = lane >> 5;

  int octmax = (cd.OC - (mb << 6)) >> 5; if (octmax > 2) octmax = 2;

  f32x16 acc00 = {}, acc01 = {}, acc10 = {}, acc11 = {};

  int aofs = SWO + kq * 512 + l31 * 8;
  int bofs = kq * SPL + (MASKED ? (((wid << 1) * 36 + 1 + l31) * 8)
                                : ((wid * 68 + l31) * 8));

  const bf16_t* wtc = P.wt + cd.wt_off;
  int icgs = cd.IC >> 3;
  int nchunks = cd.IC >> 4;

  auto stage_sin = [&](int cb, int buf) {
    int ic0 = cb << 4;
    for (int g = wid; g < 2 * NSG; g += 8) {
      int p = (g >= NSG) ? 1 : 0;
      int gi = g - p * NSG;
      int s = (gi << 6) + lane;
      int rr = s / COLS, cc = s - rr * COLS;
      int h = hblk + rr - 2;
      const bf16_t* gp;
      if (!MASKED) {
        int w = cc - 2;
        bool inb = (s < REAL) && ((unsigned)h < 64u) && ((unsigned)w < 64u);
        gp = inb ? (P.yt + (size_t)((((b << 6) + (h & 63)) << 6) | (w & 63)) * CTOT
                        + cd.chs + ic0 + (p << 3))
                 : P.zp;
      } else {
        int j = cc - 1;
        bool inb = (s < REAL) && ((unsigned)h < 64u) && ((unsigned)j < 32u);
        gp = inb ? (P.ytp + (size_t)((((b << 6) + (h & 63)) << 5) + (j & 31)) * CTOT
                         + cd.chs + ic0 + (p << 3))
                 : P.zp;
      }
      gload16(gp, S + buf * SINB + p * SPL + (gi << 9));
    }
  };
  // stage one tap-group's weights into Sw slot-buffer swb (0 or 1)
  auto stage_sw = [&](int gstart, int gcnt, int swb, int cb) {
    int ic0 = cb << 4;
    for (int t = wid; t < 2 * gcnt; t += 8) {
      int slot = t >> 1, icg = t & 1;
      int ti = gstart + slot;
      int tap = MASKED ? (2 * ti + 1) : ti;
      const bf16_t* gp = wtc +
          (size_t)((tap * icgs + (ic0 >> 3) + icg) * cd.OCp + (mb << 6) + lane) * 8;
      gload16(gp, S + SWO + ((swb * 7 + slot) << 10) + (icg << 9));
    }
  };

#define TAP_ONE(TI, SL)                                                         \
    {                                                                           \
      int tap_ = MASKED ? (2 * (TI) + 1) : (TI);                                \
      int dy_ = tap_ / 5, dx_ = tap_ % 5;                                       \
      bf16x8 af0 = *(const bf16x8*)(S + aofs + (SL) * 1024);                    \
      bf16x8 bf0, bf1;                                                          \
      if (!MASKED) {                                                            \
        int toff_ = (dy_ * 68 + dx_) * 8;                                       \
        bf0 = *(const bf16x8*)(Sn + bofs + toff_);                              \
        bf1 = *(const bf16x8*)(Sn + bofs + toff_ + 256);                        \
      } else {                                                                  \
        int j0_ = (dx_ - 1 - (dy_ & 1)) / 2;                                    \
        int j1_ = (dx_ - 2 - ((dy_ + 1) & 1)) / 2;                              \
        bf0 = *(const bf16x8*)(Sn + bofs + (dy_ * 36 + j0_) * 8);               \
        bf1 = *(const bf16x8*)(Sn + bofs + ((dy_ + 1) * 36 + j1_) * 8);         \
      }                                                                         \
      acc00 = __builtin_amdgcn_mfma_f32_32x32x16_bf16(af0, bf0, acc00, 0, 0, 0);\
      acc01 = __builtin_amdgcn_mfma_f32_32x32x16_bf16(af0, bf1, acc01, 0, 0, 0);\
      if (octmax > 1) {                                                         \
        bf16x8 af1 = *(const bf16x8*)(S + aofs + (SL) * 1024 + 256);            \
        acc10 = __builtin_amdgcn_mfma_f32_32x32x16_bf16(af1, bf0, acc10, 0,0,0);\
        acc11 = __builtin_amdgcn_mfma_f32_32x32x16_bf16(af1, bf1, acc11, 0,0,0);\
      }                                                                         \
    }
#define RUNG(GS, SB, CNT)                                                       \
    _Pragma("unroll")                                                           \
    for (int s_ = 0; s_ < (CNT); ++s_) TAP_ONE((GS) + s_, (SB) + s_)

  stage_sin(0, 0);
  stage_sw(0, MASKED ? 6 : 7, 0, 0);
  for (int cb = 0; cb < nchunks; ++cb) {
    const bf16_t* Sn = S + (cb & 1) * SINB;
    __syncthreads();                      // drains Sin(cb) + G0(cb) [issued last group]
    if (!MASKED) {
      stage_sw(7, 6, 1, cb);              // G1 -> swbuf1, lands under G0's 7 taps
      RUNG(0, 0, 7)
      __syncthreads();                    // drains G1
      stage_sw(13, 6, 0, cb);             // G2 -> swbuf0
      RUNG(7, 7, 6)
      __syncthreads();                    // drains G2
      stage_sw(19, 6, 1, cb);             // G3 -> swbuf1
      RUNG(13, 0, 6)
      __syncthreads();                    // drains G3
      if (cb + 1 < nchunks) {
        stage_sin(cb + 1, (cb + 1) & 1);  // lands under G3's taps, drained @ top
        stage_sw(0, 7, 0, cb + 1);        // G0(cb+1)
      }
      RUNG(19, 7, 6)
    } else {
      stage_sw(6, 6, 1, cb);              // G1 -> swbuf1
      RUNG(0, 0, 6)
      __syncthreads();                    // drains G1
      if (cb + 1 < nchunks) {
        stage_sin(cb + 1, (cb + 1) & 1);
        stage_sw(0, 6, 0, cb + 1);
      }
      RUNG(6, 7, 6)
    }
  }
#undef RUNG
#undef TAP_ONE

  // ---- epilogue: bias (+ parity packing for masked) ----
  float* outp = P.out + cd.out_off;
#define EPI_U(A, OT, PT)                                                        \
  {                                                                             \
    int h = hblk + wid;                                                         \
    _Pragma("unroll")                                                           \
    for (int r = 0; r < 16; ++r) {                                              \
      int row = (r & 3) + ((r >> 2) << 3) + (kq << 2);                          \
      int oc = (mb << 6) + ((OT) << 5) + row;                                   \
      outp[(size_t)(b * cd.OC + oc) * 4096 + (h << 6) + ((PT) << 5) + l31] =    \
          (A)[r] + cd.bias[oc];                                                 \
    }                                                                           \
  }
#define EPI_M(A, OT, PT)                                                        \
  {                                                                             \
    int h = hblk + (wid << 1) + (PT);                                           \
    _Pragma("unroll")                                                           \
    for (int r = 0; r < 16; ++r) {                                              \
      int row = (r & 3) + ((r >> 2) << 3) + (kq << 2);                          \
      int oc = (mb << 6) + ((OT) << 5) + row;                                   \
      float val = (A)[r] + cd.bias[oc];                                         \
      float2 pr;                                                                \
      if ((PT) == 0) { pr.x = 0.0f; pr.y = val; }                               \
      else           { pr.x = val;  pr.y = 0.0f; }                              \
      *(float2*)(outp + (size_t)(b * cd.OC + oc) * 4096 + (h << 6) + (l31 << 1)) = pr; \
    }                                                                           \
  }
  if (!MASKED) {
    EPI_U(acc00, 0, 0); EPI_U(acc01, 0, 1);
    if (octmax > 1) { EPI_U(acc10, 1, 0); EPI_U(acc11, 1, 1); }
  } else {
    EPI_M(acc00, 0, 0); EPI_M(acc01, 0, 1);
    if (octmax > 1) { EPI_M(acc10, 1, 0); EPI_M(acc11, 1, 1); }
  }
#undef EPI_U
#undef EPI_M
}

__global__ __launch_bounds__(512, 4) void k_conv_main(MainParams P) {
  // unmasked max: 2*13312 (Sin dbuf) + 14*1024 (Sw) = 40960 el = 81920 B
  // -> exactly 2 blocks/CU (160 KB), 16 waves/CU
  __shared__ bf16_t S[40960];
  int bid = blockIdx.x;
  int ci = 0;
#pragma unroll
  for (int i = 1; i < 9; ++i) if (bid >= P.cv[i].job_start) ci = i;
  ConvDesc cd = P.cv[ci];
  int local = bid - cd.job_start;
  if (cd.masked) conv_run<true>(cd, P, local, S);
  else           conv_run<false>(cd, P, local, S);
}

extern "C" void kernel_launch(void* const* d_in, const int* in_sizes, int n_in,
                              void* d_out, int out_size, void* d_ws, size_t ws_size,
                              hipStream_t stream) {
  const float* y = (const float*)d_in[0];
  bf16_t* yt  = (bf16_t*)d_ws;                               // 10,485,760 el
  bf16_t* ytp = yt + (size_t)NPIX * CTOT;                    // +5,242,880 el
  bf16_t* wt  = ytp + (size_t)(NPIX / 2) * CTOT;             // +3,660,800 el
  bf16_t* zp  = wt + 3660800;                                // +512 el (1 KB zeros)

  k_transpose_y<<<2560, 256, 0, stream>>>(y, yt, ytp);
  k_zero<<<1, 64, 0, stream>>>((uint4*)zp);

  // Heaviest-first:      ch4      sp4     ch3     ch2     ch1     sp3     sp2     sp1    sp0
  static const int ICv[9]  = {128,    192,    64,     32,     16,     64,     32,     16,    16};
  static const int OCv[9]  = {384,    384,    128,    64,     32,     128,    64,     32,    32};
  static const int OCp[9]  = {384,    384,    128,    64,     64,     128,    64,     64,    64};
  static const int WIDX[9] = {19,     11,     17,     15,     13,     9,      7,      5,     3};
  static const int BIDX[9] = {20,     12,     18,     16,     14,     10,     8,      6,     4};
  static const int CHS[9]  = {0,      128,    0,      0,      0,      64,     32,     16,    0};
  static const int MSK[9]  = {0,      1,      0,      0,      0,      1,      1,      1,     1};
  static const int WTOFF[9] = {0, 1228800, 3072000, 3276800, 3328000,
                               3353600, 3558400, 3609600, 3635200};
  static const int OUTOFF[9] = {28311552, 15728640, 11534336, 5242880, 2097152,
                                7340032,  3145728,  1048576,  0};
  // blocks: unmasked (OCp/64)*64, masked (OCp/64)*32  (r5 geometry)
  static const int JOBST[9] = {0, 384, 576, 704, 768, 832, 896, 928, 960};  // total 992

  for (int i = 0; i < 9; ++i) {
    int n = OCp[i] * ICv[i];
    k_transpose_w<<<(n + 255) / 256, 256, 0, stream>>>(
        (const float*)d_in[WIDX[i]], wt + WTOFF[i], ICv[i], OCv[i], OCp[i]);
  }

  MainParams P;
  P.yt = yt; P.ytp = ytp; P.wt = wt; P.zp = zp; P.out = (float*)d_out;
  for (int i = 0; i < 9; ++i) {
    P.cv[i].bias = (const float*)d_in[BIDX[i]];
    P.cv[i].out_off = OUTOFF[i];
    P.cv[i].wt_off = WTOFF[i];
    P.cv[i].IC = ICv[i]; P.cv[i].OC = OCv[i]; P.cv[i].OCp = OCp[i];
    P.cv[i].chs = CHS[i]; P.cv[i].masked = MSK[i];
    P.cv[i].job_start = JOBST[i];
  }
  k_conv_main<<<992, 512, 0, stream>>>(P);
}

// Round 12
// 157.680 us; speedup vs baseline: 1.3783x; 1.1846x over previous
//
#include <hip/hip_runtime.h>

typedef __bf16 bf16_t;
typedef __bf16 bf16x8 __attribute__((ext_vector_type(8)));
typedef float f32x16 __attribute__((ext_vector_type(16)));
typedef unsigned int u32;

#define CTOT 320
#define NPIX 32768  // 8*64*64

// global -> LDS direct DMA, 16 B per lane; LDS dest = wave-uniform base + lane*16
__device__ __forceinline__ void gload16(const void* g, void* l) {
  __builtin_amdgcn_global_load_lds((const __attribute__((address_space(1))) u32*)g,
                                   (__attribute__((address_space(3))) u32*)l, 16, 0, 0);
}

// Raw barrier with role-conditional counted drain (T3/T4): only waves with
// `wait` drain their own vmcnt FIFO; others sail through. sched_barrier(0)
// fences stop the compiler moving DMA/ds_read across the barrier.
__device__ __forceinline__ void sync_drain(bool wait) {
  if (wait) asm volatile("s_waitcnt vmcnt(0)" ::: "memory");
  __builtin_amdgcn_sched_barrier(0);
  __builtin_amdgcn_s_barrier();
  __builtin_amdgcn_sched_barrier(0);
}

// ---------- merged prep: y transpose (+packed), 9 weight transposes, zero page
struct PrepParams {
  const float* y;
  bf16_t *yt, *ytp, *wt;
  const float* w[9];
  int IC[9], OC[9], OCp[9], wtoff[9], jst[9];
  uint4* zp;
};

__global__ __launch_bounds__(256) void k_prep(PrepParams Q) {
  int blk = blockIdx.x, tid = threadIdx.x;
  if (blk >= 2560) {
    int wb = blk - 2560;
    if (wb >= 572) { if (tid < 64) Q.zp[tid] = uint4{0u, 0u, 0u, 0u}; return; }
    int ci = 0;
#pragma unroll
    for (int i = 1; i < 9; ++i) if (wb >= Q.jst[i]) ci = i;
    int IC = Q.IC[ci], OCp = Q.OCp[ci], OC = Q.OC[ci];
    int idx = (wb - Q.jst[ci]) * 256 + tid;
    if (idx >= OCp * IC) return;
    int oc = idx / IC, ic = idx - oc * IC;
    bool valid = (oc < OC);
    const float* src = Q.w[ci] + (size_t)(oc * IC + ic) * 25;
    bf16_t* dst = Q.wt + Q.wtoff[ci];
    int icg = ic >> 3, ie = ic & 7;
#pragma unroll
    for (int t = 0; t < 25; ++t) {
      float v = valid ? src[t] : 0.0f;
      dst[(size_t)((t * (IC >> 3) + icg) * OCp + oc) * 8 + ie] = (bf16_t)v;
    }
    return;
  }
  __shared__ bf16_t T[64][72];
  int c0 = (blk % 5) * 64;
  int bh = blk / 5;
  int b = bh >> 6, h = bh & 63;
  {
    int c = tid >> 2, w0 = (tid & 3) << 4;
    const float* src = Q.y + (size_t)(b * CTOT + c0 + c) * 4096 + (h << 6) + w0;
#pragma unroll
    for (int j = 0; j < 16; j += 4) {
      float4 v = *(const float4*)(src + j);
      T[c][w0 + j + 0] = (bf16_t)v.x;
      T[c][w0 + j + 1] = (bf16_t)v.y;
      T[c][w0 + j + 2] = (bf16_t)v.z;
      T[c][w0 + j + 3] = (bf16_t)v.w;
    }
  }
  __syncthreads();
  {
    int w = tid >> 2, cq = (tid & 3) << 4;
    union { uint4 v; bf16_t b[8]; } u0, u1;
#pragma unroll
    for (int j = 0; j < 8; ++j) { u0.b[j] = T[cq + j][w]; u1.b[j] = T[cq + 8 + j][w]; }
    bf16_t* dst = Q.yt + (size_t)((bh << 6) | w) * CTOT + c0 + cq;
    *(uint4*)dst = u0.v;
    *(uint4*)(dst + 8) = u1.v;
  }
  if (tid < 128) {  // packed even-checkerboard copy: w = 2j + (h&1)
    int j = tid >> 2, cq = (tid & 3) << 4;
    int w = (j << 1) + (h & 1);
    union { uint4 v; bf16_t b[8]; } u0, u1;
#pragma unroll
    for (int k = 0; k < 8; ++k) { u0.b[k] = T[cq + k][w]; u1.b[k] = T[cq + 8 + k][w]; }
    bf16_t* dst = Q.ytp + (size_t)((bh << 5) + j) * CTOT + c0 + cq;
    *(uint4*)dst = u0.v;
    *(uint4*)(dst + 8) = u1.v;
  }
}

// ---------- main conv ----------
struct ConvDesc {
  const float* bias;
  int out_off, wt_off;
  int IC, OC, OCp, chs, masked, job_start;
};
struct MainParams {
  const bf16_t* yt;
  const bf16_t* ytp;
  const bf16_t* wt;
  const bf16_t* zp;
  float* out;
  ConvDesc cv[9];
};

template <bool MASKED>
__device__ __forceinline__ void conv_run(const ConvDesc cd, const MainParams& P,
                                         int local, bf16_t* S) {
  constexpr int COLS = MASKED ? 36 : 68;
  constexpr int REAL = MASKED ? 720 : 816;
  constexpr int NSG  = MASKED ? 12 : 13;
  constexpr int SPL  = NSG * 512;
  constexpr int SINB = 2 * SPL;
  constexpr int SWO  = 2 * SINB;

  int mb = MASKED ? (local >> 5) : (local >> 6);
  int nb = local & (MASKED ? 31 : 63);
  int b  = MASKED ? (nb >> 2) : (nb >> 3);
  int hblk = MASKED ? ((nb & 3) << 4) : ((nb & 7) << 3);
  int tid = threadIdx.x, lane = tid & 63, wid = tid >> 6;
  int l31 = lane & 31, kq = lane >> 5;
  bool sin_role = (wid < 4);   // waves 0-3: Sin DMA; waves 4-7: Sw DMA

  int octmax = (cd.OC - (mb << 6)) >> 5; if (octmax > 2) octmax = 2;

  f32x16 acc00 = {}, acc01 = {}, acc10 = {}, acc11 = {};

  int aofs = SWO + kq * 512 + l31 * 8;
  int bofs = kq * SPL + (MASKED ? (((wid << 1) * 36 + 1 + l31) * 8)
                                : ((wid * 68 + l31) * 8));

  const bf16_t* wtc = P.wt + cd.wt_off;
  int icgs = cd.IC >> 3;
  int nchunks = cd.IC >> 4;

  // Sin staging: waves 0-3 only (their vmcnt holds ONLY Sin loads)
  auto stage_sin = [&](int cb, int buf) {
    int ic0 = cb << 4;
    for (int g = wid; g < 2 * NSG; g += 4) {
      int p = (g >= NSG) ? 1 : 0;
      int gi = g - p * NSG;
      int s = (gi << 6) + lane;
      int rr = s / COLS, cc = s - rr * COLS;
      int h = hblk + rr - 2;
      const bf16_t* gp;
      if (!MASKED) {
        int w = cc - 2;
        bool inb = (s < REAL) && ((unsigned)h < 64u) && ((unsigned)w < 64u);
        gp = inb ? (P.yt + (size_t)((((b << 6) + (h & 63)) << 6) | (w & 63)) * CTOT
                        + cd.chs + ic0 + (p << 3))
                 : P.zp;
      } else {
        int j = cc - 1;
        bool inb = (s < REAL) && ((unsigned)h < 64u) && ((unsigned)j < 32u);
        gp = inb ? (P.ytp + (size_t)((((b << 6) + (h & 63)) << 5) + (j & 31)) * CTOT
                         + cd.chs + ic0 + (p << 3))
                 : P.zp;
      }
      gload16(gp, S + buf * SINB + p * SPL + (gi << 9));
    }
  };
  // Sw staging: waves 4-7 only
  auto stage_sw = [&](int gstart, int gcnt, int swb, int cb) {
    int ic0 = cb << 4;
    for (int t = wid - 4; t < 2 * gcnt; t += 4) {
      int slot = t >> 1, icg = t & 1;
      int ti = gstart + slot;
      int tap = MASKED ? (2 * ti + 1) : ti;
      const bf16_t* gp = wtc +
          (size_t)((tap * icgs + (ic0 >> 3) + icg) * cd.OCp + (mb << 6) + lane) * 8;
      gload16(gp, S + SWO + ((swb * 7 + slot) << 10) + (icg << 9));
    }
  };

#define TAP_ONE(TI, SL)                                                         \
    {                                                                           \
      int tap_ = MASKED ? (2 * (TI) + 1) : (TI);                                \
      int dy_ = tap_ / 5, dx_ = tap_ % 5;                                       \
      bf16x8 af0 = *(const bf16x8*)(S + aofs + (SL) * 1024);                    \
      bf16x8 bf0, bf1;                                                          \
      if (!MASKED) {                                                            \
        int toff_ = (dy_ * 68 + dx_) * 8;                                       \
        bf0 = *(const bf16x8*)(Sn + bofs + toff_);                              \
        bf1 = *(const bf16x8*)(Sn + bofs + toff_ + 256);                        \
      } else {                                                                  \
        int j0_ = (dx_ - 1 - (dy_ & 1)) / 2;                                    \
        int j1_ = (dx_ - 2 - ((dy_ + 1) & 1)) / 2;                              \
        bf0 = *(const bf16x8*)(Sn + bofs + (dy_ * 36 + j0_) * 8);               \
        bf1 = *(const bf16x8*)(Sn + bofs + ((dy_ + 1) * 36 + j1_) * 8);         \
      }                                                                         \
      acc00 = __builtin_amdgcn_mfma_f32_32x32x16_bf16(af0, bf0, acc00, 0, 0, 0);\
      acc01 = __builtin_amdgcn_mfma_f32_32x32x16_bf16(af0, bf1, acc01, 0, 0, 0);\
      if (octmax > 1) {                                                         \
        bf16x8 af1 = *(const bf16x8*)(S + aofs + (SL) * 1024 + 256);            \
        acc10 = __builtin_amdgcn_mfma_f32_32x32x16_bf16(af1, bf0, acc10, 0,0,0);\
        acc11 = __builtin_amdgcn_mfma_f32_32x32x16_bf16(af1, bf1, acc11, 0,0,0);\
      }                                                                         \
    }
#define RUNG(GS, SB, CNT)                                                       \
    __builtin_amdgcn_s_setprio(1);                                              \
    _Pragma("unroll")                                                           \
    for (int s_ = 0; s_ < (CNT); ++s_) TAP_ONE((GS) + s_, (SB) + s_)            \
    __builtin_amdgcn_s_setprio(0);

  if (sin_role) stage_sin(0, 0);
  else          stage_sw(0, MASKED ? 6 : 7, 0, 0);

  for (int cb = 0; cb < nchunks; ++cb) {
    const bf16_t* Sn = S + (cb & 1) * SINB;
    sync_drain(true);                        // top: each role drains its own queue
    if (sin_role) {
      if (cb + 1 < nchunks) stage_sin(cb + 1, (cb + 1) & 1);  // full chunk to land
    }
    if (!MASKED) {
      if (!sin_role) stage_sw(7, 6, 1, cb);  // G1 -> slots 7..12
      RUNG(0, 0, 7)                          // G0 @ slots 0..6
      sync_drain(!sin_role);                 // Sw waves drain G1 only
      if (!sin_role) stage_sw(13, 6, 0, cb); // G2 -> slots 0..5
      RUNG(7, 7, 6)                          // G1
      sync_drain(!sin_role);
      if (!sin_role) stage_sw(19, 6, 1, cb); // G3 -> slots 7..12
      RUNG(13, 0, 6)                         // G2
      sync_drain(!sin_role);
      if (!sin_role && cb + 1 < nchunks) stage_sw(0, 7, 0, cb + 1);  // G0'
      RUNG(19, 7, 6)                         // G3
    } else {
      if (!sin_role) stage_sw(6, 6, 1, cb);  // G1 -> slots 7..12
      RUNG(0, 0, 6)                          // G0 @ slots 0..5
      sync_drain(!sin_role);
      if (!sin_role && cb + 1 < nchunks) stage_sw(0, 6, 0, cb + 1);
      RUNG(6, 7, 6)                          // G1
    }
  }
#undef RUNG
#undef TAP_ONE

  // ---- epilogue: bias (+ parity packing for masked) ----
  float* outp = P.out + cd.out_off;
#define EPI_U(A, OT, PT)                                                        \
  {                                                                             \
    int h = hblk + wid;                                                         \
    _Pragma("unroll")                                                           \
    for (int r = 0; r < 16; ++r) {                                              \
      int row = (r & 3) + ((r >> 2) << 3) + (kq << 2);                          \
      int oc = (mb << 6) + ((OT) << 5) + row;                                   \
      outp[(size_t)(b * cd.OC + oc) * 4096 + (h << 6) + ((PT) << 5) + l31] =    \
          (A)[r] + cd.bias[oc];                                                 \
    }                                                                           \
  }
#define EPI_M(A, OT, PT)                                                        \
  {                                                                             \
    int h = hblk + (wid << 1) + (PT);                                           \
    _Pragma("unroll")                                                           \
    for (int r = 0; r < 16; ++r) {                                              \
      int row = (r & 3) + ((r >> 2) << 3) + (kq << 2);                          \
      int oc = (mb << 6) + ((OT) << 5) + row;                                   \
      float val = (A)[r] + cd.bias[oc];                                         \
      float2 pr;                                                                \
      if ((PT) == 0) { pr.x = 0.0f; pr.y = val; }                               \
      else           { pr.x = val;  pr.y = 0.0f; }                              \
      *(float2*)(outp + (size_t)(b * cd.OC + oc) * 4096 + (h << 6) + (l31 << 1)) = pr; \
    }                                                                           \
  }
  if (!MASKED) {
    EPI_U(acc00, 0, 0); EPI_U(acc01, 0, 1);
    if (octmax > 1) { EPI_U(acc10, 1, 0); EPI_U(acc11, 1, 1); }
  } else {
    EPI_M(acc00, 0, 0); EPI_M(acc01, 0, 1);
    if (octmax > 1) { EPI_M(acc10, 1, 0); EPI_M(acc11, 1, 1); }
  }
#undef EPI_U
#undef EPI_M
}

__global__ __launch_bounds__(512, 4) void k_conv_main(MainParams P) {
  __shared__ bf16_t S[40960];   // 81920 B -> exactly 2 blocks/CU
  int bid = blockIdx.x;
  int ci = 0;
#pragma unroll
  for (int i = 1; i < 9; ++i) if (bid >= P.cv[i].job_start) ci = i;
  ConvDesc cd = P.cv[ci];
  int local = bid - cd.job_start;
  if (cd.masked) conv_run<true>(cd, P, local, S);
  else           conv_run<false>(cd, P, local, S);
}

extern "C" void kernel_launch(void* const* d_in, const int* in_sizes, int n_in,
                              void* d_out, int out_size, void* d_ws, size_t ws_size,
                              hipStream_t stream) {
  const float* y = (const float*)d_in[0];
  bf16_t* yt  = (bf16_t*)d_ws;                               // 10,485,760 el
  bf16_t* ytp = yt + (size_t)NPIX * CTOT;                    // +5,242,880 el
  bf16_t* wt  = ytp + (size_t)(NPIX / 2) * CTOT;             // +3,660,800 el
  bf16_t* zp  = wt + 3660800;                                // +512 el (1 KB zeros)

  // Heaviest-first:      ch4      sp4     ch3     ch2     ch1     sp3     sp2     sp1    sp0
  static const int ICv[9]  = {128,    192,    64,     32,     16,     64,     32,     16,    16};
  static const int OCv[9]  = {384,    384,    128,    64,     32,     128,    64,     32,    32};
  static const int OCp[9]  = {384,    384,    128,    64,     64,     128,    64,     64,    64};
  static const int WIDX[9] = {19,     11,     17,     15,     13,     9,      7,      5,     3};
  static const int BIDX[9] = {20,     12,     18,     16,     14,     10,     8,      6,     4};
  static const int CHS[9]  = {0,      128,    0,      0,      0,      64,     32,     16,    0};
  static const int MSK[9]  = {0,      1,      0,      0,      0,      1,      1,      1,     1};
  static const int WTOFF[9] = {0, 1228800, 3072000, 3276800, 3328000,
                               3353600, 3558400, 3609600, 3635200};
  static const int OUTOFF[9] = {28311552, 15728640, 11534336, 5242880, 2097152,
                                7340032,  3145728,  1048576,  0};
  static const int JOBST[9] = {0, 384, 576, 704, 768, 832, 896, 928, 960};  // total 992
  // prep weight-block starts: ceil(OCp*IC/256) = {192,288,32,8,4,32,8,4,4}
  static const int PJST[9] = {0, 192, 480, 512, 520, 524, 556, 564, 568};   // total 572

  PrepParams Q;
  Q.y = y; Q.yt = yt; Q.ytp = ytp; Q.wt = wt; Q.zp = (uint4*)zp;
  for (int i = 0; i < 9; ++i) {
    Q.w[i] = (const float*)d_in[WIDX[i]];
    Q.IC[i] = ICv[i]; Q.OC[i] = OCv[i]; Q.OCp[i] = OCp[i];
    Q.wtoff[i] = WTOFF[i]; Q.jst[i] = PJST[i];
  }
  k_prep<<<3133, 256, 0, stream>>>(Q);   // 2560 y-blocks + 572 w-blocks + 1 zero

  MainParams P;
  P.yt = yt; P.ytp = ytp; P.wt = wt; P.zp = zp; P.out = (float*)d_out;
  for (int i = 0; i < 9; ++i) {
    P.cv[i].bias = (const float*)d_in[BIDX[i]];
    P.cv[i].out_off = OUTOFF[i];
    P.cv[i].wt_off = WTOFF[i];
    P.cv[i].IC = ICv[i]; P.cv[i].OC = OCv[i]; P.cv[i].OCp = OCp[i];
    P.cv[i].chs = CHS[i]; P.cv[i].masked = MSK[i];
    P.cv[i].job_start = JOBST[i];
  }
  k_conv_main<<<992, 512, 0, stream>>>(P);
}